// Round 7
// baseline (551.430 us; speedup 1.0000x reference)
//
#include <hip/hip_runtime.h>
#include <hip/hip_bf16.h>
#include <stdint.h>

// BaseLayer MoE block. I/O f32, GEMMs bf16 MFMA. T=8192, D=1024, F=4096, E=8.
// R7: 4-phase GEMM schedule (halved barrier/lgkm events vs R6's 8-phase, same
// LDS traffic): phase = (buf, k-half), all MR*NR MFMAs per phase, uniform
// counted vmcnt at every phase close (never 0 in steady state).

#define T_TOK 8192
#define DM    1024
#define FF    4096
#define NE    8
#define CAP   1024

typedef __attribute__((ext_vector_type(8))) __bf16 bf16x8;
typedef __attribute__((ext_vector_type(4))) float  f32x4;

__device__ __forceinline__ unsigned short f2bf(float f) {
  unsigned u = __float_as_uint(f);
  u += 0x7FFFu + ((u >> 16) & 1u);   // round-to-nearest-even
  return (unsigned short)(u >> 16);
}
__device__ __forceinline__ void gload_lds16(const void* g, void* l) {
  __builtin_amdgcn_global_load_lds(
      (const __attribute__((address_space(1))) unsigned int*)(uintptr_t)g,
      (__attribute__((address_space(3))) unsigned int*)l, 16, 0, 0);
}
template <int NN> __device__ __forceinline__ void vmw() {
  asm volatile("s_waitcnt vmcnt(%0)" :: "i"(NN) : "memory");
}

// ---------------- LN + centroid scores (scores stored [E][T]) ---------------
__global__ __launch_bounds__(256) void ln_scores_k(
    const float* __restrict__ x, const float* __restrict__ g,
    const float* __restrict__ b, const float* __restrict__ cent,
    unsigned short* __restrict__ nrm, float* __restrict__ scores) {
  const int t = blockIdx.x, tid = threadIdx.x;
  const int lane = tid & 63, w = tid >> 6;
  float4 v = ((const float4*)(x + (size_t)t * DM))[tid];
  float f0 = v.x, f1 = v.y, f2 = v.z, f3 = v.w;
  float s = f0 + f1 + f2 + f3;
  float sq = f0 * f0 + f1 * f1 + f2 * f2 + f3 * f3;
#pragma unroll
  for (int o = 32; o > 0; o >>= 1) { s += __shfl_xor(s, o); sq += __shfl_xor(sq, o); }
  __shared__ float red[8];
  if (lane == 0) { red[w] = s; red[4 + w] = sq; }
  __syncthreads();
  float S = red[0] + red[1] + red[2] + red[3];
  float SQ = red[4] + red[5] + red[6] + red[7];
  float mu = S * (1.0f / DM);
  float var = SQ * (1.0f / DM) - mu * mu;
  float rstd = rsqrtf(var + 1e-5f);
  float4 gv = ((const float4*)g)[tid];
  float4 bv = ((const float4*)b)[tid];
  float n0 = (f0 - mu) * rstd * gv.x + bv.x;
  float n1 = (f1 - mu) * rstd * gv.y + bv.y;
  float n2 = (f2 - mu) * rstd * gv.z + bv.z;
  float n3 = (f3 - mu) * rstd * gv.w + bv.w;
  ushort4 o4;
  o4.x = f2bf(n0); o4.y = f2bf(n1); o4.z = f2bf(n2); o4.w = f2bf(n3);
  ((ushort4*)(nrm + (size_t)t * DM))[tid] = o4;
  __shared__ float sred[4];
  for (int e = 0; e < NE; ++e) {
    float4 cv = ((const float4*)(cent + e * DM))[tid];
    float p = n0 * cv.x + n1 * cv.y + n2 * cv.z + n3 * cv.w;
#pragma unroll
    for (int o = 32; o > 0; o >>= 1) p += __shfl_xor(p, o);
    if (lane == 0) sred[w] = p;
    __syncthreads();
    if (tid == 0) scores[(size_t)e * T_TOK + t] = sred[0] + sred[1] + sred[2] + sred[3];
    __syncthreads();
  }
}

// ---- wave-0 helpers for the assignment (64 lanes, lockstep) ----------------
__device__ __forceinline__ void pivot_scan(const unsigned* hist, unsigned* S) {
  const int l = threadIdx.x;
  unsigned v0 = hist[4 * l], v1 = hist[4 * l + 1];
  unsigned v2 = hist[4 * l + 2], v3 = hist[4 * l + 3];
  unsigned own = v0 + v1 + v2 + v3;
  unsigned s = own;
#pragma unroll
  for (int off = 1; off < 64; off <<= 1) {
    unsigned t = __shfl_down(s, off);
    if (l + off < 64) s += t;
  }
  unsigned i3 = (s - own) + v3;
  unsigned i2 = i3 + v2;
  unsigned i1 = i2 + v1;
  unsigned i0 = i1 + v0;
  unsigned need = S[0];
  if (i0 >= need && i0 - v0 < need) { S[1] = 4 * l + 0; S[0] = need - (i0 - v0); }
  if (i1 >= need && i1 - v1 < need) { S[1] = 4 * l + 1; S[0] = need - (i1 - v1); }
  if (i2 >= need && i2 - v2 < need) { S[1] = 4 * l + 2; S[0] = need - (i2 - v2); }
  if (i3 >= need && i3 - v3 < need) { S[1] = 4 * l + 3; S[0] = need - (i3 - v3); }
}
__device__ __forceinline__ void tie_select(const unsigned* bmap, unsigned* S,
                                           int* tokdst, unsigned char* taken) {
  const int l = threadIdx.x;
  unsigned wds[4] = {bmap[4 * l], bmap[4 * l + 1], bmap[4 * l + 2], bmap[4 * l + 3]};
  unsigned cnt = __popc(wds[0]) + __popc(wds[1]) + __popc(wds[2]) + __popc(wds[3]);
  unsigned p = cnt;
#pragma unroll
  for (int off = 1; off < 64; off <<= 1) {
    unsigned t = __shfl_up(p, off);
    if (l >= off) p += t;
  }
  unsigned base = p - cnt;
  const unsigned r = S[0];
#pragma unroll
  for (int c = 0; c < 4; ++c) {
    unsigned word = wds[c];
    while (word && base < r) {
      int b = __ffs(word) - 1; word &= word - 1;
      int i = (4 * l + c) * 32 + b;
      unsigned pp = atomicAdd(&S[2], 1u);
      tokdst[pp] = i; taken[i] = 1;
      ++base;
    }
    base += __popc(word);
  }
}

// ---- assignment body: greedy per-expert exact top-C (jax top_k ties) -------
__device__ void assign_body(const float* __restrict__ scores,
                            int* __restrict__ tok, char* smem) {
  unsigned*       key   = (unsigned*)smem;                   // 32 KB
  unsigned short* candA = (unsigned short*)(smem + 32768);   // 16 KB
  unsigned short* candB = (unsigned short*)(smem + 49152);   // 16 KB
  unsigned char*  taken = (unsigned char*)(smem + 65536);    //  8 KB
  unsigned*       hist  = (unsigned*)(smem + 73728);         //  1 KB
  unsigned*       bmap  = (unsigned*)(smem + 74752);         //  1 KB
  unsigned*       S     = (unsigned*)(smem + 75776);         // scalars
  const int tid = threadIdx.x;
  for (int i = tid; i < T_TOK; i += 1024) taken[i] = 0;
  __syncthreads();
  for (int e = 0; e < NE; ++e) {
    const float* se = scores + (size_t)e * T_TOK;
    if (tid < 256) hist[tid] = 0;
    if (tid == 0) { S[0] = CAP; S[2] = 0; S[4] = 0; }
    __syncthreads();
#pragma unroll
    for (int j = 0; j < 8; ++j) {
      int i = j * 1024 + tid;
      unsigned k = 0;
      if (!taken[i]) {
        unsigned bb = __float_as_uint(se[i]);
        k = (bb & 0x80000000u) ? ~bb : (bb | 0x80000000u);   // order-preserving
      }
      key[i] = k;
      atomicAdd(&hist[k >> 24], 1u);
    }
    __syncthreads();
    if (tid < 64) pivot_scan(hist, S);
    __syncthreads();
    {
      const unsigned pb = S[1];
#pragma unroll
      for (int j = 0; j < 8; ++j) {
        int i = j * 1024 + tid;
        unsigned by = key[i] >> 24;
        if (by > pb) {
          unsigned p = atomicAdd(&S[2], 1u);
          tok[e * CAP + p] = i; taken[i] = 1;
        } else if (by == pb) {
          unsigned q = atomicAdd(&S[4], 1u);
          candA[q] = (unsigned short)i;
        }
      }
    }
    __syncthreads();
    unsigned short* cur = candA;
    unsigned short* nxt = candB;
    for (int shift = 16; shift >= 0; shift -= 8) {
      const unsigned m = S[4];
      __syncthreads();
      if (tid < 256) hist[tid] = 0;
      if (tid == 0) S[4] = 0;
      __syncthreads();
      for (unsigned q = tid; q < m; q += 1024)
        atomicAdd(&hist[(key[cur[q]] >> shift) & 255u], 1u);
      __syncthreads();
      if (tid < 64) pivot_scan(hist, S);
      __syncthreads();
      const unsigned pb = S[1];
      for (unsigned q = tid; q < m; q += 1024) {
        unsigned i = cur[q];
        unsigned by = (key[i] >> shift) & 255u;
        if (by > pb) {
          unsigned p = atomicAdd(&S[2], 1u);
          tok[e * CAP + p] = (int)i; taken[i] = 1;
        } else if (by == pb) {
          unsigned t2 = atomicAdd(&S[4], 1u);
          nxt[t2] = (unsigned short)i;
        }
      }
      __syncthreads();
      unsigned short* tmp = cur; cur = nxt; nxt = tmp;
    }
    if (tid < 256) bmap[tid] = 0;
    __syncthreads();
    {
      const unsigned m = S[4];
      for (unsigned q = tid; q < m; q += 1024) {
        unsigned i = cur[q];
        atomicOr(&bmap[i >> 5], 1u << (i & 31));
      }
    }
    __syncthreads();
    if (tid < 64) tie_select(bmap, S, tok + e * CAP, taken);
    __syncthreads();
  }
}

// ---- fat kernel: block 0 = assignment; blocks 1.. = weight transpose -------
__global__ __launch_bounds__(1024) void fat_assign_transpose(
    const float* __restrict__ scores, int* __restrict__ tok,
    const float* __restrict__ w1, const float* __restrict__ w2,
    unsigned short* __restrict__ w1T, unsigned short* __restrict__ w2T) {
  __shared__ __align__(16) char smem[77824];
  if (blockIdx.x == 0) { assign_body(scores, tok, smem); return; }
  const int tix = blockIdx.x - 1;
  const int which = tix >> 11;           // 2048 tiles each
  const int r = tix & 2047;
  const int e = r >> 8;
  const int rr = r & 255;
  int K, N, nt, kt;
  const float* s;
  unsigned short* d;
  if (which == 0) { K = DM; N = FF; nt = rr & 31; kt = rr >> 5; s = w1; d = w1T; }
  else            { K = FF; N = DM; nt = rr & 7;  kt = rr >> 3; s = w2; d = w2T; }
  s += (size_t)e * K * N;
  d += (size_t)e * N * K;
  const int q = threadIdx.x >> 8, t2 = threadIdx.x & 255;
  const int k0 = kt * 128 + (q >> 1) * 64;
  const int n0 = nt * 128 + (q & 1) * 64;
  float (*t)[65] = (float (*)[65])(smem + q * 16640);
  for (int p = t2; p < 1024; p += 256) {
    int rw = p >> 4, c4 = (p & 15) * 4;
    float4 v = *(const float4*)(s + (size_t)(k0 + rw) * N + n0 + c4);
    t[c4 + 0][rw] = v.x; t[c4 + 1][rw] = v.y;
    t[c4 + 2][rw] = v.z; t[c4 + 3][rw] = v.w;
  }
  __syncthreads();
  for (int p = t2; p < 512; p += 256) {
    int c = p >> 3, r8 = (p & 7) * 8;
    unsigned short tmp[8];
#pragma unroll
    for (int i = 0; i < 8; ++i) tmp[i] = f2bf(t[c][r8 + i]);
    *(uint4*)(d + (size_t)(n0 + c) * K + k0 + r8) = *(const uint4*)tmp;
  }
}

// ------- 4-phase MFMA GEMM: C = A[MxK] * Bt[NxK]^T + XCD swizzle ------------
// Phase = (buf, k-half): NR+MR ds_reads, one A+B stage, counted vmcnt, bar,
// lgkm(0), MR*NR MFMA, bar. 8 barriers / 2 K-tiles (vs 16 in R6).
template <int EPI, bool GATHER, int K, int N, int BN, int WM, int WN>
__global__ __launch_bounds__(512, 2) void gemm_4ph(
    const unsigned short* __restrict__ A, const unsigned short* __restrict__ Bt,
    const float* __restrict__ bias, const int* __restrict__ tok,
    const float* __restrict__ xres, void* __restrict__ Cout) {
  constexpr int BM = 256;
  constexpr int NT = K / 64;
  constexpr int NITER = NT / 2;
  constexpr int RM = BM / WM, RN = BN / WN;
  constexpr int MR = RM / 16, NR = RN / 16;
  constexpr int ALD = 2;
  constexpr int BLD = BN / 128;
  constexpr int LD  = ALD + BLD;         // loads per stage (A+B of one k-half)
  constexpr int VMN = 2 * LD;            // steady-state counted wait
  constexpr int ASH = BM * 32;
  constexpr int BSH = BN * 32;
  constexpr int BUFS = 2 * ASH + 2 * BSH;
  __shared__ __align__(16) unsigned short lds[2 * BUFS];
  __shared__ int tokl[BM];

  // XCD-aware chunked swizzle (nwg % 8 == 0)
  const int flat = blockIdx.x + gridDim.x * (blockIdx.y + gridDim.y * blockIdx.z);
  const int nwg = gridDim.x * gridDim.y * gridDim.z;
  const int nf = (flat & 7) * (nwg >> 3) + (flat >> 3);
  const int bx = nf % gridDim.x;
  const int rem = nf / gridDim.x;
  const int e  = rem / gridDim.y;
  const int n0 = bx * BN, m0 = (rem % gridDim.y) * BM;

  const int tid = threadIdx.x, lane = tid & 63, w = tid >> 6;
  const int wr = w / WN, wc = w % WN;
  const int lr = lane & 15, lk = lane >> 4;

  for (int i = tid; i < BM; i += 512) tokl[i] = tok[e * CAP + m0 + i];
  __syncthreads();

  const unsigned short* aptr[ALD];
  const unsigned short* bptr[BLD];
  const unsigned short* Be = Bt + (size_t)e * N * K + (size_t)n0 * K;
#pragma unroll
  for (int i = 0; i < ALD; ++i) {
    int c = i * 512 + tid, row = c >> 2, sp = c & 3;
    int s = sp ^ ((row >> 1) & 3);
    size_t grow = GATHER ? (size_t)tokl[row] : (size_t)(e * CAP + m0 + row);
    aptr[i] = A + grow * K + s * 8;
  }
#pragma unroll
  for (int i = 0; i < BLD; ++i) {
    int c = i * 512 + tid, row = c >> 2, sp = c & 3;
    int s = sp ^ ((row >> 1) & 3);
    bptr[i] = Be + (size_t)row * K + s * 8;
  }
  auto stage = [&](int tile, int kh) {
#pragma unroll
    for (int i = 0; i < ALD; ++i)
      gload_lds16(aptr[i] + tile * 64 + kh * 32,
                  lds + (size_t)(tile & 1) * BUFS + kh * ASH + (i * 512 + tid) * 8);
#pragma unroll
    for (int i = 0; i < BLD; ++i)
      gload_lds16(bptr[i] + tile * 64 + kh * 32,
                  lds + (size_t)(tile & 1) * BUFS + 2 * ASH + kh * BSH + (i * 512 + tid) * 8);
  };

  const int swz = (lr >> 1) & 3;
  const int afo = (wr * RM + lr) * 32 + (lk ^ swz) * 8;
  const int bfo = (wc * RN + lr) * 32 + (lk ^ swz) * 8;

  f32x4 acc[MR][NR] = {};

  // phase: reads + optional stage + counted vmcnt + bar + lgkm + MFMA + bar
  auto phase = [&](int buf, int kh, bool dostage, int st, int sk, int vmv) {
    bf16x8 af[MR], bfr[NR];
#pragma unroll
    for (int ni = 0; ni < NR; ++ni)
      bfr[ni] = *(const bf16x8*)(lds + (size_t)buf * BUFS + 2 * ASH +
                                 kh * BSH + bfo + ni * 512);
#pragma unroll
    for (int mi = 0; mi < MR; ++mi)
      af[mi] = *(const bf16x8*)(lds + (size_t)buf * BUFS + kh * ASH + afo +
                                mi * 512);
    if (dostage) stage(st, sk);
    if (vmv == 0) vmw<0>();
    else if (vmv == 3) vmw<3>();
    else if (vmv == 4) vmw<4>();
    else if (vmv == 6) vmw<6>();
    else vmw<8>();
    __builtin_amdgcn_s_barrier();
    asm volatile("s_waitcnt lgkmcnt(0)" ::: "memory");
    __builtin_amdgcn_sched_barrier(0);
    __builtin_amdgcn_s_setprio(1);
#pragma unroll
    for (int mi = 0; mi < MR; ++mi)
#pragma unroll
      for (int ni = 0; ni < NR; ++ni)
        acc[mi][ni] = __builtin_amdgcn_mfma_f32_16x16x32_bf16(
            af[mi], bfr[ni], acc[mi][ni], 0, 0, 0);
    __builtin_amdgcn_s_setprio(0);
    __builtin_amdgcn_s_barrier();
  };

  // prologue: tile0 both halves + tile1 kh0; wait leaves last 2 stages
  stage(0, 0); stage(0, 1); stage(1, 0);
  vmw<VMN>();
  __builtin_amdgcn_s_barrier();

#pragma unroll 1
  for (int it = 0; it < NITER; ++it) {
    const int ta = 2 * it, tb = ta + 1;
    if (it + 1 < NITER) {
      phase(0, 0, true, tb, 1, VMN);      // stage (tb,kh1)  -> read this P3
      phase(0, 1, true, ta + 2, 0, VMN);  // stage next ta kh0 -> next P0
      phase(1, 0, true, ta + 2, 1, VMN);  // stage next ta kh1 -> next P1
      phase(1, 1, true, tb + 2, 0, VMN);  // stage next tb kh0 -> next P2
    } else {
      phase(0, 0, true, tb, 1, VMN);
      phase(0, 1, false, 0, 0, LD);       // ensure prev P3's stage landed
      phase(1, 0, false, 0, 0, 0);        // drain: (tb,kh1) ready for P3
      phase(1, 1, false, 0, 0, 0);
    }
  }

  // ---- epilogue
  const int lg = lane >> 4;
#pragma unroll
  for (int ni = 0; ni < NR; ++ni) {
    const int n = n0 + wc * RN + ni * 16 + lr;
    const float bb = bias[e * N + n];
#pragma unroll
    for (int mi = 0; mi < MR; ++mi) {
#pragma unroll
      for (int r = 0; r < 4; ++r) {
        const int ml = wr * RM + mi * 16 + lg * 4 + r;
        float v = acc[mi][ni][r] + bb;
        if (EPI == 1) {
          float z = 1.5957691216f * v + 0.07135481283f * v * v * v;
          float gl = v / (1.0f + __expf(-z));
          ((unsigned short*)Cout)[(size_t)(e * CAP + m0 + ml) * N + n] = f2bf(gl);
        } else {
          const int token = tokl[ml];
          v += xres[(size_t)token * DM + n];
          ((float*)Cout)[(size_t)token * (size_t)N + n] = v;
        }
      }
    }
  }
}

// ---------------- launch ----------------------------------------------------
extern "C" void kernel_launch(void* const* d_in, const int* in_sizes, int n_in,
                              void* d_out, int out_size, void* d_ws, size_t ws_size,
                              hipStream_t stream) {
  const float* x    = (const float*)d_in[0];
  const float* cent = (const float*)d_in[1];
  const float* ln_g = (const float*)d_in[2];
  const float* ln_b = (const float*)d_in[3];
  const float* w1   = (const float*)d_in[4];
  const float* b1   = (const float*)d_in[5];
  const float* w2   = (const float*)d_in[6];
  const float* b2   = (const float*)d_in[7];
  float* out = (float*)d_out;

  char* ws = (char*)d_ws;
  size_t off = 0;
  unsigned short* w1T = (unsigned short*)(ws + off); off += (size_t)NE * FF * DM * 2;
  unsigned short* w2T = (unsigned short*)(ws + off); off += (size_t)NE * DM * FF * 2;
  unsigned short* nrm = (unsigned short*)(ws + off); off += (size_t)T_TOK * DM * 2;
  unsigned short* h1  = (unsigned short*)(ws + off); off += (size_t)T_TOK * FF * 2;
  float* scores       = (float*)(ws + off);          off += (size_t)NE * T_TOK * 4;
  int* tok            = (int*)(ws + off);            off += (size_t)T_TOK * 4;

  ln_scores_k<<<dim3(T_TOK), 256, 0, stream>>>(x, ln_g, ln_b, cent, nrm, scores);
  fat_assign_transpose<<<dim3(1 + 4096), 1024, 0, stream>>>(
      scores, tok, w1, w2, w1T, w2T);
  gemm_4ph<1, true, DM, FF, 256, 2, 4>
      <<<dim3(FF / 256, CAP / 256, NE), 512, 0, stream>>>(nrm, w1T, b1, tok, nullptr, h1);
  gemm_4ph<2, false, FF, DM, 128, 4, 2>
      <<<dim3(DM / 128, CAP / 256, NE), 512, 0, stream>>>(h1, w2T, b2, tok, x, out);
}

// Round 9
// 356.823 us; speedup vs baseline: 1.5454x; 1.5454x over previous
//
#include <hip/hip_runtime.h>
#include <hip/hip_bf16.h>
#include <stdint.h>

// BaseLayer MoE block. I/O f32, GEMMs bf16 MFMA. T=8192, D=1024, F=4096, E=8.
// R9: R8 (split-K GEMM2 + combine) with the final-iteration vmcnt race fixed:
// last K-iter's p3 does vmcnt(0) (steady-state p3 drains (tb,0)+(tb,1); final
// iter staged nothing at p2/p3 so vmcnt(3) left (tb,1) unfenced for p6/p7).

#define T_TOK 8192
#define DM    1024
#define FF    4096
#define NE    8
#define CAP   1024

typedef __attribute__((ext_vector_type(8))) __bf16 bf16x8;
typedef __attribute__((ext_vector_type(4))) float  f32x4;

__device__ __forceinline__ unsigned short f2bf(float f) {
  unsigned u = __float_as_uint(f);
  u += 0x7FFFu + ((u >> 16) & 1u);   // round-to-nearest-even
  return (unsigned short)(u >> 16);
}
__device__ __forceinline__ void gload_lds16(const void* g, void* l) {
  __builtin_amdgcn_global_load_lds(
      (const __attribute__((address_space(1))) unsigned int*)(uintptr_t)g,
      (__attribute__((address_space(3))) unsigned int*)l, 16, 0, 0);
}

// ---------------- LN + centroid scores (scores stored [E][T]) ---------------
__global__ __launch_bounds__(256) void ln_scores_k(
    const float* __restrict__ x, const float* __restrict__ g,
    const float* __restrict__ b, const float* __restrict__ cent,
    unsigned short* __restrict__ nrm, float* __restrict__ scores) {
  const int t = blockIdx.x, tid = threadIdx.x;
  const int lane = tid & 63, w = tid >> 6;
  float4 v = ((const float4*)(x + (size_t)t * DM))[tid];
  float f0 = v.x, f1 = v.y, f2 = v.z, f3 = v.w;
  float s = f0 + f1 + f2 + f3;
  float sq = f0 * f0 + f1 * f1 + f2 * f2 + f3 * f3;
#pragma unroll
  for (int o = 32; o > 0; o >>= 1) { s += __shfl_xor(s, o); sq += __shfl_xor(sq, o); }
  __shared__ float red[8];
  if (lane == 0) { red[w] = s; red[4 + w] = sq; }
  __syncthreads();
  float S = red[0] + red[1] + red[2] + red[3];
  float SQ = red[4] + red[5] + red[6] + red[7];
  float mu = S * (1.0f / DM);
  float var = SQ * (1.0f / DM) - mu * mu;
  float rstd = rsqrtf(var + 1e-5f);
  float4 gv = ((const float4*)g)[tid];
  float4 bv = ((const float4*)b)[tid];
  float n0 = (f0 - mu) * rstd * gv.x + bv.x;
  float n1 = (f1 - mu) * rstd * gv.y + bv.y;
  float n2 = (f2 - mu) * rstd * gv.z + bv.z;
  float n3 = (f3 - mu) * rstd * gv.w + bv.w;
  ushort4 o4;
  o4.x = f2bf(n0); o4.y = f2bf(n1); o4.z = f2bf(n2); o4.w = f2bf(n3);
  ((ushort4*)(nrm + (size_t)t * DM))[tid] = o4;
  __shared__ float sred[4];
  for (int e = 0; e < NE; ++e) {
    float4 cv = ((const float4*)(cent + e * DM))[tid];
    float p = n0 * cv.x + n1 * cv.y + n2 * cv.z + n3 * cv.w;
#pragma unroll
    for (int o = 32; o > 0; o >>= 1) p += __shfl_xor(p, o);
    if (lane == 0) sred[w] = p;
    __syncthreads();
    if (tid == 0) scores[(size_t)e * T_TOK + t] = sred[0] + sred[1] + sred[2] + sred[3];
    __syncthreads();
  }
}

// ---- wave-0 helpers for the assignment (64 lanes, lockstep) ----------------
__device__ __forceinline__ void pivot_scan(const unsigned* hist, unsigned* S) {
  const int l = threadIdx.x;
  unsigned v0 = hist[4 * l], v1 = hist[4 * l + 1];
  unsigned v2 = hist[4 * l + 2], v3 = hist[4 * l + 3];
  unsigned own = v0 + v1 + v2 + v3;
  unsigned s = own;
#pragma unroll
  for (int off = 1; off < 64; off <<= 1) {
    unsigned t = __shfl_down(s, off);
    if (l + off < 64) s += t;
  }
  unsigned i3 = (s - own) + v3;
  unsigned i2 = i3 + v2;
  unsigned i1 = i2 + v1;
  unsigned i0 = i1 + v0;
  unsigned need = S[0];
  if (i0 >= need && i0 - v0 < need) { S[1] = 4 * l + 0; S[0] = need - (i0 - v0); }
  if (i1 >= need && i1 - v1 < need) { S[1] = 4 * l + 1; S[0] = need - (i1 - v1); }
  if (i2 >= need && i2 - v2 < need) { S[1] = 4 * l + 2; S[0] = need - (i2 - v2); }
  if (i3 >= need && i3 - v3 < need) { S[1] = 4 * l + 3; S[0] = need - (i3 - v3); }
}
__device__ __forceinline__ void tie_select(const unsigned* bmap, unsigned* S,
                                           int* tokdst, unsigned char* taken) {
  const int l = threadIdx.x;
  unsigned wds[4] = {bmap[4 * l], bmap[4 * l + 1], bmap[4 * l + 2], bmap[4 * l + 3]};
  unsigned cnt = __popc(wds[0]) + __popc(wds[1]) + __popc(wds[2]) + __popc(wds[3]);
  unsigned p = cnt;
#pragma unroll
  for (int off = 1; off < 64; off <<= 1) {
    unsigned t = __shfl_up(p, off);
    if (l >= off) p += t;
  }
  unsigned base = p - cnt;
  const unsigned r = S[0];
#pragma unroll
  for (int c = 0; c < 4; ++c) {
    unsigned word = wds[c];
    while (word && base < r) {
      int b = __ffs(word) - 1; word &= word - 1;
      int i = (4 * l + c) * 32 + b;
      unsigned pp = atomicAdd(&S[2], 1u);
      tokdst[pp] = i; taken[i] = 1;
      ++base;
    }
    base += __popc(word);
  }
}

// ---- assignment body: greedy per-expert exact top-C (jax top_k ties) -------
__device__ void assign_body(const float* __restrict__ scores,
                            int* __restrict__ tok, char* smem) {
  unsigned*       key   = (unsigned*)smem;                   // 32 KB
  unsigned short* candA = (unsigned short*)(smem + 32768);   // 16 KB
  unsigned short* candB = (unsigned short*)(smem + 49152);   // 16 KB
  unsigned char*  taken = (unsigned char*)(smem + 65536);    //  8 KB
  unsigned*       hist  = (unsigned*)(smem + 73728);         //  1 KB
  unsigned*       bmap  = (unsigned*)(smem + 74752);         //  1 KB
  unsigned*       S     = (unsigned*)(smem + 75776);         // scalars
  const int tid = threadIdx.x;
  for (int i = tid; i < T_TOK; i += 1024) taken[i] = 0;
  __syncthreads();
  for (int e = 0; e < NE; ++e) {
    const float* se = scores + (size_t)e * T_TOK;
    if (tid < 256) hist[tid] = 0;
    if (tid == 0) { S[0] = CAP; S[2] = 0; S[4] = 0; }
    __syncthreads();
#pragma unroll
    for (int j = 0; j < 8; ++j) {
      int i = j * 1024 + tid;
      unsigned k = 0;
      if (!taken[i]) {
        unsigned bb = __float_as_uint(se[i]);
        k = (bb & 0x80000000u) ? ~bb : (bb | 0x80000000u);   // order-preserving
      }
      key[i] = k;
      atomicAdd(&hist[k >> 24], 1u);
    }
    __syncthreads();
    if (tid < 64) pivot_scan(hist, S);
    __syncthreads();
    {
      const unsigned pb = S[1];
#pragma unroll
      for (int j = 0; j < 8; ++j) {
        int i = j * 1024 + tid;
        unsigned by = key[i] >> 24;
        if (by > pb) {
          unsigned p = atomicAdd(&S[2], 1u);
          tok[e * CAP + p] = i; taken[i] = 1;
        } else if (by == pb) {
          unsigned q = atomicAdd(&S[4], 1u);
          candA[q] = (unsigned short)i;
        }
      }
    }
    __syncthreads();
    unsigned short* cur = candA;
    unsigned short* nxt = candB;
    for (int shift = 16; shift >= 0; shift -= 8) {
      const unsigned m = S[4];
      __syncthreads();
      if (tid < 256) hist[tid] = 0;
      if (tid == 0) S[4] = 0;
      __syncthreads();
      for (unsigned q = tid; q < m; q += 1024)
        atomicAdd(&hist[(key[cur[q]] >> shift) & 255u], 1u);
      __syncthreads();
      if (tid < 64) pivot_scan(hist, S);
      __syncthreads();
      const unsigned pb = S[1];
      for (unsigned q = tid; q < m; q += 1024) {
        unsigned i = cur[q];
        unsigned by = (key[i] >> shift) & 255u;
        if (by > pb) {
          unsigned p = atomicAdd(&S[2], 1u);
          tok[e * CAP + p] = (int)i; taken[i] = 1;
        } else if (by == pb) {
          unsigned t2 = atomicAdd(&S[4], 1u);
          nxt[t2] = (unsigned short)i;
        }
      }
      __syncthreads();
      unsigned short* tmp = cur; cur = nxt; nxt = tmp;
    }
    if (tid < 256) bmap[tid] = 0;
    __syncthreads();
    {
      const unsigned m = S[4];
      for (unsigned q = tid; q < m; q += 1024) {
        unsigned i = cur[q];
        atomicOr(&bmap[i >> 5], 1u << (i & 31));
      }
    }
    __syncthreads();
    if (tid < 64) tie_select(bmap, S, tok + e * CAP, taken);
    __syncthreads();
  }
}

// ---- fat kernel: block 0 = assignment; blocks 1.. = weight transpose -------
__global__ __launch_bounds__(1024) void fat_assign_transpose(
    const float* __restrict__ scores, int* __restrict__ tok,
    const float* __restrict__ w1, const float* __restrict__ w2,
    unsigned short* __restrict__ w1T, unsigned short* __restrict__ w2T) {
  __shared__ __align__(16) char smem[77824];
  if (blockIdx.x == 0) { assign_body(scores, tok, smem); return; }
  const int tix = blockIdx.x - 1;
  const int which = tix >> 11;           // 2048 tiles each
  const int r = tix & 2047;
  const int e = r >> 8;
  const int rr = r & 255;
  int K, N, nt, kt;
  const float* s;
  unsigned short* d;
  if (which == 0) { K = DM; N = FF; nt = rr & 31; kt = rr >> 5; s = w1; d = w1T; }
  else            { K = FF; N = DM; nt = rr & 7;  kt = rr >> 3; s = w2; d = w2T; }
  s += (size_t)e * K * N;
  d += (size_t)e * N * K;
  const int q = threadIdx.x >> 8, t2 = threadIdx.x & 255;
  const int k0 = kt * 128 + (q >> 1) * 64;
  const int n0 = nt * 128 + (q & 1) * 64;
  float (*t)[65] = (float (*)[65])(smem + q * 16640);
  for (int p = t2; p < 1024; p += 256) {
    int rw = p >> 4, c4 = (p & 15) * 4;
    float4 v = *(const float4*)(s + (size_t)(k0 + rw) * N + n0 + c4);
    t[c4 + 0][rw] = v.x; t[c4 + 1][rw] = v.y;
    t[c4 + 2][rw] = v.z; t[c4 + 3][rw] = v.w;
  }
  __syncthreads();
  for (int p = t2; p < 512; p += 256) {
    int c = p >> 3, r8 = (p & 7) * 8;
    unsigned short tmp[8];
#pragma unroll
    for (int i = 0; i < 8; ++i) tmp[i] = f2bf(t[c][r8 + i]);
    *(uint4*)(d + (size_t)(n0 + c) * K + k0 + r8) = *(const uint4*)tmp;
  }
}

// ------- 8-phase MFMA GEMM + LDA + split-K (final-iter vmcnt fixed) ---------
// EPI==1: +bias, gelu -> bf16 h1 (GATHER A rows by tok)
// EPI==2: +bias +xres, scatter f32 out (fallback, no split)
// EPI==3: f32 partial -> Cout[ks][T][DM] dense (split-K; bias/res in combine)
template <int EPI, bool GATHER, int K, int LDA, int N, int BN, int WM, int WN>
__global__ __launch_bounds__(512, 2) void gemm_8ph(
    const unsigned short* __restrict__ A, const unsigned short* __restrict__ Bt,
    const float* __restrict__ bias, const int* __restrict__ tok,
    const float* __restrict__ xres, void* __restrict__ Cout) {
  constexpr int BM = 256;
  constexpr int NT = K / 64;
  constexpr int NITER = NT / 2;
  constexpr int RM = BM / WM, RN = BN / WN;
  constexpr int MR = RM / 16, NR = RN / 16, MH = MR / 2;
  constexpr int ALD = 2;
  constexpr int BLD = BN / 128;
  constexpr int ASH = BM * 32;
  constexpr int BSH = BN * 32;
  constexpr int BUFS = 2 * ASH + 2 * BSH;
  __shared__ __align__(16) unsigned short lds[2 * BUFS];
  __shared__ int tokl[BM];

  // XCD-aware chunked swizzle (nwg % 8 == 0)
  const int flat = blockIdx.x + gridDim.x * (blockIdx.y + gridDim.y * blockIdx.z);
  const int nwg = gridDim.x * gridDim.y * gridDim.z;
  const int nf = (flat & 7) * (nwg >> 3) + (flat >> 3);
  const int bx = nf % gridDim.x;
  const int rem = nf / gridDim.x;
  const int zz = rem / gridDim.y;
  const int e  = (EPI == 3) ? (zz >> 1) : zz;
  const int ks = (EPI == 3) ? (zz & 1) : 0;
  const int koff = ks * K;
  const int n0 = bx * BN, m0 = (rem % gridDim.y) * BM;

  const int tid = threadIdx.x, lane = tid & 63, w = tid >> 6;
  const int wr = w / WN, wc = w % WN;
  const int lr = lane & 15, lk = lane >> 4;

  if (GATHER || EPI == 2) {
    for (int i = tid; i < BM; i += 512) tokl[i] = tok[e * CAP + m0 + i];
    __syncthreads();
  }

  const unsigned short* aptr[ALD];
  const unsigned short* bptr[BLD];
  const unsigned short* Be = Bt + (size_t)e * N * LDA + (size_t)n0 * LDA + koff;
#pragma unroll
  for (int i = 0; i < ALD; ++i) {
    int c = i * 512 + tid, row = c >> 2, sp = c & 3;
    int s = sp ^ ((row >> 1) & 3);
    size_t grow = GATHER ? (size_t)tokl[row] : (size_t)(e * CAP + m0 + row);
    aptr[i] = A + grow * LDA + koff + s * 8;
  }
#pragma unroll
  for (int i = 0; i < BLD; ++i) {
    int c = i * 512 + tid, row = c >> 2, sp = c & 3;
    int s = sp ^ ((row >> 1) & 3);
    bptr[i] = Be + (size_t)row * LDA + s * 8;
  }
  auto stageA = [&](int tile, int kh) {
#pragma unroll
    for (int i = 0; i < ALD; ++i)
      gload_lds16(aptr[i] + tile * 64 + kh * 32,
                  lds + (size_t)(tile & 1) * BUFS + kh * ASH + (i * 512 + tid) * 8);
  };
  auto stageB = [&](int tile, int kh) {
#pragma unroll
    for (int i = 0; i < BLD; ++i)
      gload_lds16(bptr[i] + tile * 64 + kh * 32,
                  lds + (size_t)(tile & 1) * BUFS + 2 * ASH + kh * BSH + (i * 512 + tid) * 8);
  };

  const int swz = (lr >> 1) & 3;
  const int afo = (wr * RM + lr) * 32 + (lk ^ swz) * 8;
  const int bfo = (wc * RN + lr) * 32 + (lk ^ swz) * 8;

  f32x4 acc[MR][NR] = {};

  stageA(0, 0); stageB(0, 0); stageA(0, 1); stageB(0, 1);
  stageA(1, 0); stageB(1, 0);
  asm volatile("s_waitcnt vmcnt(%0)" :: "i"(ALD + BLD) : "memory");
  __builtin_amdgcn_s_barrier();

#pragma unroll 1
  for (int it = 0; it < NITER; ++it) {
    const int ta = 2 * it, tb = 2 * it + 1;
    const bool last = (it + 1 == NITER);
    bf16x8 bfr[NR], af[MH];
#pragma unroll
    for (int p = 0; p < 8; ++p) {
      const int buf = p >> 2, kh = (p >> 1) & 1, mh = p & 1;
      if (mh == 0) {
#pragma unroll
        for (int ni = 0; ni < NR; ++ni)
          bfr[ni] = *(const bf16x8*)(lds + (size_t)buf * BUFS + 2 * ASH +
                                     kh * BSH + bfo + ni * 512);
      }
#pragma unroll
      for (int j = 0; j < MH; ++j)
        af[j] = *(const bf16x8*)(lds + (size_t)buf * BUFS + kh * ASH + afo +
                                 (mh * MH + j) * 512);
      if (p == 0)      {                       stageA(tb, 1);     stageB(tb, 1); }
      else if (p == 2) { if (ta + 2 < NT)      stageA(ta + 2, 0); }
      else if (p == 3) { if (ta + 2 < NT)      stageB(ta + 2, 0); }
      else if (p == 4) { if (ta + 2 < NT)    { stageA(ta + 2, 1); stageB(ta + 2, 1); } }
      else if (p == 6) { if (tb + 2 < NT)      stageA(tb + 2, 0); }
      else if (p == 7) { if (tb + 2 < NT)      stageB(tb + 2, 0); }
      // RACE FIX: steady-state p3 vmcnt(ALD+BLD) drains (tb,0)+(tb,1) because
      // p2/p3 staged 3 new loads; in the LAST iteration nothing was staged, so
      // vmcnt(ALD+BLD) would leave (tb,1) in flight while p6/p7 read it.
      if (p == 3) {
        if (last) asm volatile("s_waitcnt vmcnt(0)" ::: "memory");
        else      asm volatile("s_waitcnt vmcnt(%0)" :: "i"(ALD + BLD) : "memory");
      } else if (p == 7) {
        if (!last) asm volatile("s_waitcnt vmcnt(%0)" :: "i"(ALD + BLD) : "memory");
      }
      __builtin_amdgcn_s_barrier();
      asm volatile("s_waitcnt lgkmcnt(0)" ::: "memory");
      __builtin_amdgcn_sched_barrier(0);
      __builtin_amdgcn_s_setprio(1);
#pragma unroll
      for (int j = 0; j < MH; ++j)
#pragma unroll
        for (int ni = 0; ni < NR; ++ni)
          acc[mh * MH + j][ni] = __builtin_amdgcn_mfma_f32_16x16x32_bf16(
              af[j], bfr[ni], acc[mh * MH + j][ni], 0, 0, 0);
      __builtin_amdgcn_s_setprio(0);
      __builtin_amdgcn_s_barrier();
    }
  }

  const int lg = lane >> 4;
#pragma unroll
  for (int ni = 0; ni < NR; ++ni) {
    const int n = n0 + wc * RN + ni * 16 + lr;
    const float bb = (EPI == 3) ? 0.0f : bias[e * N + n];
#pragma unroll
    for (int mi = 0; mi < MR; ++mi) {
#pragma unroll
      for (int r = 0; r < 4; ++r) {
        const int ml = wr * RM + mi * 16 + lg * 4 + r;
        float v = acc[mi][ni][r] + bb;
        if (EPI == 1) {
          float z = 1.5957691216f * v + 0.07135481283f * v * v * v;
          float gl = v / (1.0f + __expf(-z));
          ((unsigned short*)Cout)[(size_t)(e * CAP + m0 + ml) * N + n] = f2bf(gl);
        } else if (EPI == 2) {
          const int token = tokl[ml];
          v += xres[(size_t)token * DM + n];
          ((float*)Cout)[(size_t)token * (size_t)N + n] = v;
        } else {
          const size_t row = (size_t)ks * T_TOK + e * CAP + m0 + ml;
          ((float*)Cout)[row * (size_t)N + n] = v;
        }
      }
    }
  }
}

// ---- combine: out[token] = part0 + part1 + b2[e] + x[token] ----------------
__global__ __launch_bounds__(256) void combine_k(
    const float* __restrict__ part, const int* __restrict__ tok,
    const float* __restrict__ b2, const float* __restrict__ x,
    float* __restrict__ out) {
  const int r = blockIdx.x;
  const int e = r >> 10;
  const int token = tok[r];
  const int d4 = threadIdx.x;
  float4 p0 = ((const float4*)(part + (size_t)r * DM))[d4];
  float4 p1 = ((const float4*)(part + (size_t)(T_TOK + r) * DM))[d4];
  float4 bb = ((const float4*)(b2 + (size_t)e * DM))[d4];
  float4 xx = ((const float4*)(x + (size_t)token * DM))[d4];
  float4 o;
  o.x = p0.x + p1.x + bb.x + xx.x;
  o.y = p0.y + p1.y + bb.y + xx.y;
  o.z = p0.z + p1.z + bb.z + xx.z;
  o.w = p0.w + p1.w + bb.w + xx.w;
  ((float4*)(out + (size_t)token * DM))[d4] = o;
}

// ---------------- launch ----------------------------------------------------
extern "C" void kernel_launch(void* const* d_in, const int* in_sizes, int n_in,
                              void* d_out, int out_size, void* d_ws, size_t ws_size,
                              hipStream_t stream) {
  const float* x    = (const float*)d_in[0];
  const float* cent = (const float*)d_in[1];
  const float* ln_g = (const float*)d_in[2];
  const float* ln_b = (const float*)d_in[3];
  const float* w1   = (const float*)d_in[4];
  const float* b1   = (const float*)d_in[5];
  const float* w2   = (const float*)d_in[6];
  const float* b2   = (const float*)d_in[7];
  float* out = (float*)d_out;

  char* ws = (char*)d_ws;
  size_t off = 0;
  unsigned short* w1T = (unsigned short*)(ws + off); off += (size_t)NE * FF * DM * 2;
  unsigned short* w2T = (unsigned short*)(ws + off); off += (size_t)NE * DM * FF * 2;
  unsigned short* nrm = (unsigned short*)(ws + off); off += (size_t)T_TOK * DM * 2;
  unsigned short* h1  = (unsigned short*)(ws + off); off += (size_t)T_TOK * FF * 2;
  float* scores       = (float*)(ws + off);          off += (size_t)NE * T_TOK * 4;
  int* tok            = (int*)(ws + off);            off += (size_t)T_TOK * 4;
  float* part         = (float*)(ws + off);          off += (size_t)2 * T_TOK * DM * 4;
  const bool use_split = (ws_size >= off);

  ln_scores_k<<<dim3(T_TOK), 256, 0, stream>>>(x, ln_g, ln_b, cent, nrm, scores);
  fat_assign_transpose<<<dim3(1 + 4096), 1024, 0, stream>>>(
      scores, tok, w1, w2, w1T, w2T);
  gemm_8ph<1, true, DM, DM, FF, 256, 2, 4>
      <<<dim3(FF / 256, CAP / 256, NE), 512, 0, stream>>>(nrm, w1T, b1, tok, nullptr, h1);
  if (use_split) {
    // split-K=2: z = e*2+ks, 512 blocks; partials dense, no scatter
    gemm_8ph<3, false, FF / 2, FF, DM, 128, 4, 2>
        <<<dim3(DM / 128, CAP / 256, NE * 2), 512, 0, stream>>>(
            h1, w2T, nullptr, tok, nullptr, part);
    combine_k<<<dim3(T_TOK), 256, 0, stream>>>(part, tok, b2, x, out);
  } else {
    gemm_8ph<2, false, FF, FF, DM, 128, 4, 2>
        <<<dim3(DM / 128, CAP / 256, NE), 512, 0, stream>>>(h1, w2T, b2, tok, x, out);
  }
}